// Round 10
// baseline (3198.398 us; speedup 1.0000x reference)
//
#include <hip/hip_runtime.h>

#define BB    2      // batches
#define NN    8192   // points per batch
#define CC    64     // extra feature channels
#define NPT   1024   // npoint
#define NT    128    // 64-wide tiles per dim (8192/64)
#define NBLK  16     // fallback: blocks per batch
#define TPB   512    // fallback: threads per block (1 point per thread)

// monotonic order-preserving key for f32 (handles negatives)
__device__ __forceinline__ unsigned int fkey(float v) {
  unsigned int u = __float_as_uint(v);
  return (u & 0x80000000u) ? ~u : (u | 0x80000000u);
}

// wave64 max-reduce of u32 via DPP (rocPRIM pattern); result broadcast via
// readlane(63). Prefix-max over rows (shr 1/2/4/8) then row_bcast 15/31.
__device__ __forceinline__ unsigned wave_max_u32(unsigned x) {
  int v = (int)x, t;
  t = __builtin_amdgcn_update_dpp(v, v, 0x111, 0xf, 0xf, false);  // row_shr:1
  v = ((unsigned)t > (unsigned)v) ? t : v;
  t = __builtin_amdgcn_update_dpp(v, v, 0x112, 0xf, 0xf, false);  // row_shr:2
  v = ((unsigned)t > (unsigned)v) ? t : v;
  t = __builtin_amdgcn_update_dpp(v, v, 0x114, 0xf, 0xf, false);  // row_shr:4
  v = ((unsigned)t > (unsigned)v) ? t : v;
  t = __builtin_amdgcn_update_dpp(v, v, 0x118, 0xf, 0xf, false);  // row_shr:8
  v = ((unsigned)t > (unsigned)v) ? t : v;
  t = __builtin_amdgcn_update_dpp(v, v, 0x142, 0xa, 0xf, false);  // row_bcast:15
  v = ((unsigned)t > (unsigned)v) ? t : v;
  t = __builtin_amdgcn_update_dpp(v, v, 0x143, 0xc, 0xf, false);  // row_bcast:31
  v = ((unsigned)t > (unsigned)v) ? t : v;
  return (unsigned)__builtin_amdgcn_readlane(v, 63);
}

// ======================= D-path: dist build (per batch) =======================
// D[i][j] = n_i + n_j - 2*dot(A_i,A_j); norms and dots all accumulated by
// ascending-k fmaf chains over identical tile values -> D[i][i] == 0 bit-exactly,
// and values bit-match the (absmax=0-verified) fallback formula.
// 82% of fp32 vector peak (R9) — done.
__global__ __launch_bounds__(256) void dist_kernel(
    const float* __restrict__ Pb,    // (N,3) for this batch
    const float* __restrict__ Fb,    // (C,N) for this batch
    float* __restrict__ Db) {        // (N,N) out
  __shared__ __align__(16) float Ai[67][64];
  __shared__ __align__(16) float Aj[67][64];
  __shared__ float ni_s[64], nj_s[64];
  const int bid = blockIdx.x;
  const int bi  = bid >> 7, bj = bid & (NT - 1);
  const int t   = threadIdx.x;
  const int i0  = bi * 64, j0 = bj * 64;

  for (int idx = t; idx < 67 * 64; idx += 256) {
    const int c = idx >> 6, r = idx & 63;
    float vi, vj;
    if (c < 3) {
      vi = Pb[(size_t)(i0 + r) * 3 + c];
      vj = Pb[(size_t)(j0 + r) * 3 + c];
    } else {
      vi = Fb[(size_t)(c - 3) * NN + i0 + r];
      vj = Fb[(size_t)(c - 3) * NN + j0 + r];
    }
    Ai[c][r] = vi;
    Aj[c][r] = vj;
  }
  __syncthreads();

  if (t < 64) {
    float n = 0.f;
#pragma unroll
    for (int k = 0; k < 67; ++k) n = fmaf(Ai[k][t], Ai[k][t], n);
    ni_s[t] = n;
  } else if (t < 128) {
    const int r = t - 64;
    float n = 0.f;
#pragma unroll
    for (int k = 0; k < 67; ++k) n = fmaf(Aj[k][r], Aj[k][r], n);
    nj_s[r] = n;
  }
  __syncthreads();

  const int tx = t & 15, ty = t >> 4;
  float acc[4][4] = {};
  for (int k = 0; k < 67; ++k) {
    const float4 a = *(const float4*)&Ai[k][ty * 4];
    const float4 v = *(const float4*)&Aj[k][tx * 4];
    acc[0][0] = fmaf(a.x, v.x, acc[0][0]); acc[0][1] = fmaf(a.x, v.y, acc[0][1]);
    acc[0][2] = fmaf(a.x, v.z, acc[0][2]); acc[0][3] = fmaf(a.x, v.w, acc[0][3]);
    acc[1][0] = fmaf(a.y, v.x, acc[1][0]); acc[1][1] = fmaf(a.y, v.y, acc[1][1]);
    acc[1][2] = fmaf(a.y, v.z, acc[1][2]); acc[1][3] = fmaf(a.y, v.w, acc[1][3]);
    acc[2][0] = fmaf(a.z, v.x, acc[2][0]); acc[2][1] = fmaf(a.z, v.y, acc[2][1]);
    acc[2][2] = fmaf(a.z, v.z, acc[2][2]); acc[2][3] = fmaf(a.z, v.w, acc[2][3]);
    acc[3][0] = fmaf(a.w, v.x, acc[3][0]); acc[3][1] = fmaf(a.w, v.y, acc[3][1]);
    acc[3][2] = fmaf(a.w, v.z, acc[3][2]); acc[3][3] = fmaf(a.w, v.w, acc[3][3]);
  }

  const float4 nj4 = *(const float4*)&nj_s[tx * 4];
#pragma unroll
  for (int r = 0; r < 4; ++r) {
    const float nir = ni_s[ty * 4 + r];
    float4 w;
    w.x = (nir + nj4.x) - 2.0f * acc[r][0];
    w.y = (nir + nj4.y) - 2.0f * acc[r][1];
    w.z = (nir + nj4.z) - 2.0f * acc[r][2];
    w.w = (nir + nj4.w) - 2.0f * acc[r][3];
    *(float4*)&Db[(size_t)(i0 + ty * 4 + r) * NN + j0 + tx * 4] = w;
  }
}

// ======================= D-path: serial scan =======================
// One block (512 thr, 8 waves, 1 CU) per batch; block-local sync only.
// Software-pipelined speculative preload: after each reduce we know winner
// (exact next row) and runner-up (prediction for the row after). The runner's
// row is preloaded into a ping-pong register buffer one full step early; on a
// hit the next fmin never waits on memory. Hit path reads identical bytes ->
// numerics identical. Static buffer roles via 2x-unrolled steps (no runtime
// array indexing -> no scratch).

#define CHK(val, jj) if ((val) > best) { best = (val); bj = (jj); }

#define SCAN_STEP(C0,C1,C2,C3, predC, P0,P1,P2,P3, predP, s)                   \
  {                                                                            \
    if (far != predC) {  /* miss: demand-load current row (uniform branch) */  \
      const float4* r4_ = (const float4*)(Db + (size_t)far * NN);              \
      C0 = r4_[tid]; C1 = r4_[tid + 512];                                      \
      C2 = r4_[tid + 1024]; C3 = r4_[tid + 1536];                              \
    }                                                                          \
    m0.x = fminf(m0.x, C0.x); m0.y = fminf(m0.y, C0.y);                        \
    m0.z = fminf(m0.z, C0.z); m0.w = fminf(m0.w, C0.w);                        \
    m1.x = fminf(m1.x, C1.x); m1.y = fminf(m1.y, C1.y);                        \
    m1.z = fminf(m1.z, C1.z); m1.w = fminf(m1.w, C1.w);                        \
    m2.x = fminf(m2.x, C2.x); m2.y = fminf(m2.y, C2.y);                        \
    m2.z = fminf(m2.z, C2.z); m2.w = fminf(m2.w, C2.w);                        \
    m3.x = fminf(m3.x, C3.x); m3.y = fminf(m3.y, C3.y);                        \
    m3.z = fminf(m3.z, C3.z); m3.w = fminf(m3.w, C3.w);                        \
    const int j0_ = tid * 4;                                                   \
    float best = m0.x; int bj = j0_;                                           \
    CHK(m0.y, j0_ + 1) CHK(m0.z, j0_ + 2) CHK(m0.w, j0_ + 3)                   \
    CHK(m1.x, j0_ + 2048) CHK(m1.y, j0_ + 2049)                                \
    CHK(m1.z, j0_ + 2050) CHK(m1.w, j0_ + 2051)                                \
    CHK(m2.x, j0_ + 4096) CHK(m2.y, j0_ + 4097)                                \
    CHK(m2.z, j0_ + 4098) CHK(m2.w, j0_ + 4099)                                \
    CHK(m3.x, j0_ + 6144) CHK(m3.y, j0_ + 6145)                                \
    CHK(m3.z, j0_ + 6146) CHK(m3.w, j0_ + 6147)                                \
    const unsigned fk_   = fkey(best);                                         \
    const unsigned wmax_ = wave_max_u32(fk_);                                  \
    const unsigned cand_ = (fk_ == wmax_) ? (8191u - (unsigned)bj) : 0u;       \
    const unsigned wtie_ = wave_max_u32(cand_);                                \
    if (lane == 0)                                                             \
      wred[(s) & 1][wid] = ((unsigned long long)wmax_ << 32) | wtie_;          \
    __syncthreads();  /* single barrier; parity-2 buffer is race-free */       \
    const unsigned long long* W_ = wred[(s) & 1];                              \
    const unsigned long long g0_=W_[0], g1_=W_[1], g2_=W_[2], g3_=W_[3],       \
                             g4_=W_[4], g5_=W_[5], g6_=W_[6], g7_=W_[7];       \
    unsigned long long h0_ = g0_>g1_?g0_:g1_, h1_ = g2_>g3_?g2_:g3_;           \
    unsigned long long h2_ = g4_>g5_?g4_:g5_, h3_ = g6_>g7_?g6_:g7_;           \
    unsigned long long q0_ = h0_>h1_?h0_:h1_, q1_ = h2_>h3_?h2_:h3_;           \
    const unsigned long long win_ = q0_>q1_?q0_:q1_;                           \
    far = 8191 - (int)(win_ & 0x1FFFu);                                        \
    if (tid == 0) ob[s] = far;                                                 \
    /* runner-up (keys are distinct; zero out the winner, re-max) */           \
    unsigned long long e0_ = g0_==win_?0ull:g0_, e1_ = g1_==win_?0ull:g1_;     \
    unsigned long long e2_ = g2_==win_?0ull:g2_, e3_ = g3_==win_?0ull:g3_;     \
    unsigned long long e4_ = g4_==win_?0ull:g4_, e5_ = g5_==win_?0ull:g5_;     \
    unsigned long long e6_ = g6_==win_?0ull:g6_, e7_ = g7_==win_?0ull:g7_;     \
    e0_ = e0_>e1_?e0_:e1_; e2_ = e2_>e3_?e2_:e3_;                              \
    e4_ = e4_>e5_?e4_:e5_; e6_ = e6_>e7_?e6_:e7_;                              \
    e0_ = e0_>e2_?e0_:e2_; e4_ = e4_>e6_?e4_:e6_;                              \
    const unsigned long long sec_ = e0_>e4_?e0_:e4_;                           \
    const int nrun_ = 8191 - (int)(sec_ & 0x1FFFu);                            \
    /* speculative preload of the predicted next-next row */                   \
    {                                                                          \
      const float4* p4_ = (const float4*)(Db + (size_t)nrun_ * NN);            \
      P0 = p4_[tid]; P1 = p4_[tid + 512];                                      \
      P2 = p4_[tid + 1024]; P3 = p4_[tid + 1536];                              \
      predP = nrun_;                                                           \
    }                                                                          \
  }

__global__ __attribute__((amdgpu_waves_per_eu(1, 2))) __launch_bounds__(512)
void scan_kernel(const float* __restrict__ D, unsigned long long dstride,
                 int* __restrict__ out, int ostride) {
  const int b = blockIdx.x;
  const float* Db = D + (size_t)b * dstride;
  int* ob = out + (size_t)b * ostride;
  const int tid = threadIdx.x, lane = tid & 63, wid = tid >> 6;  // 8 waves
  __shared__ unsigned long long wred[2][8];

  float4 m0 = make_float4(3.0e38f, 3.0e38f, 3.0e38f, 3.0e38f);
  float4 m1 = m0, m2 = m0, m3 = m0;
  float4 A0, A1, A2, A3, B0, B1, B2, B3;
  int far = 0, predA = -1, predB = -1;

  if (tid == 0) ob[0] = 0;

  int s = 1;
#pragma unroll 1
  for (int pair = 0; pair < (NPT - 2) / 2; ++pair) {   // 511 pairs: s=1..1022
    SCAN_STEP(A0, A1, A2, A3, predA, B0, B1, B2, B3, predB, s)
    ++s;
    SCAN_STEP(B0, B1, B2, B3, predB, A0, A1, A2, A3, predA, s)
    ++s;
  }
  SCAN_STEP(A0, A1, A2, A3, predA, B0, B1, B2, B3, predB, s)   // s = 1023
}

// ======================= fallback path (small ws; kept for safety) =======================

#define R64(M) \
  M(0) M(1) M(2) M(3) M(4) M(5) M(6) M(7) \
  M(8) M(9) M(10) M(11) M(12) M(13) M(14) M(15) \
  M(16) M(17) M(18) M(19) M(20) M(21) M(22) M(23) \
  M(24) M(25) M(26) M(27) M(28) M(29) M(30) M(31) \
  M(32) M(33) M(34) M(35) M(36) M(37) M(38) M(39) \
  M(40) M(41) M(42) M(43) M(44) M(45) M(46) M(47) \
  M(48) M(49) M(50) M(51) M(52) M(53) M(54) M(55) \
  M(56) M(57) M(58) M(59) M(60) M(61) M(62) M(63)

__global__ __attribute__((amdgpu_waves_per_eu(1, 2))) __launch_bounds__(TPB)
void fps_fallback(const float* __restrict__ pts, const float* __restrict__ feat,
                  int* __restrict__ out, unsigned long long* __restrict__ slots) {
  const int blk  = blockIdx.x & (NBLK - 1);
  const int b    = blockIdx.x >> 4;
  const int tid  = threadIdx.x;
  const int lane = tid & 63;
  const int p    = blk * TPB + tid;

  const float* Pp = pts  + (size_t)b * NN * 3 + (size_t)p * 3;
  const float* Fp = feat + (size_t)b * CC * NN + p;

  float fx = Pp[0], fy = Pp[1], fz = Pp[2];
#define DCF(i) float fc##i = Fp[(i) * NN];
  R64(DCF)
#undef DCF
  asm volatile("" : "+v"(fx), "+v"(fy), "+v"(fz));
#define PIN(i) asm volatile("" : "+v"(fc##i));
  R64(PIN)
#undef PIN

  float nrm = 0.f;
  nrm += fx * fx; nrm += fy * fy; nrm += fz * fz;
#define NR(i) nrm += fc##i * fc##i;
  R64(NR)
#undef NR

  __shared__ unsigned long long wred[TPB / 64];
  __shared__ int far_sh;

  if (blk == 0 && tid == 0) out[b * NPT] = 0;

  float mind = 3.0e38f;
  int far = 0;

  for (int s = 1; s < NPT; ++s) {
    const int fu = __builtin_amdgcn_readfirstlane(far);
    const float* Pq = pts  + (size_t)b * NN * 3 + (size_t)fu * 3;
    const float* Fq = feat + (size_t)b * CC * NN + fu;
    const float gx = Pq[0], gy = Pq[1], gz = Pq[2];
#define GL(i) const float gc##i = Fq[(i) * NN];
    R64(GL)
#undef GL
    float nf = 0.f, dot = 0.f;
    nf += gx * gx; nf += gy * gy; nf += gz * gz;
#define NF(i) nf += gc##i * gc##i;
    R64(NF)
#undef NF
    dot += fx * gx; dot += fy * gy; dot += fz * gz;
#define DT(i) dot += fc##i * gc##i;
    R64(DT)
#undef DT
    const float d = (nf + nrm) - 2.0f * dot;
    mind = fminf(mind, d);

    unsigned long long key =
        ((unsigned long long)fkey(mind) << 13) | (unsigned int)(8191 - p);
#pragma unroll
    for (int off = 1; off < 64; off <<= 1) {
      unsigned long long o = __shfl_xor(key, off);
      key = key > o ? key : o;
    }
    if (lane == 0) wred[tid >> 6] = key;
    __syncthreads();

    if (tid < 64) {
      unsigned long long bk = wred[0];
#pragma unroll
      for (int w = 1; w < TPB / 64; ++w) bk = bk > wred[w] ? bk : wred[w];
      unsigned long long* sb = slots + ((size_t)(s & 1) * BB + b) * NBLK;
      if (tid == 0) {
        bk |= ((unsigned long long)s << 45);
        __hip_atomic_store(&sb[blk], bk, __ATOMIC_RELAXED, __HIP_MEMORY_SCOPE_AGENT);
      }
      unsigned long long v = 0;
      for (;;) {
        if (tid < NBLK)
          v = __hip_atomic_load(&sb[tid], __ATOMIC_RELAXED, __HIP_MEMORY_SCOPE_AGENT);
        const bool ok = (tid < NBLK) ? ((v >> 45) == (unsigned long long)s) : true;
        if (__all(ok)) break;
        __builtin_amdgcn_s_sleep(1);
      }
#pragma unroll
      for (int off = 8; off; off >>= 1) {
        unsigned long long o = __shfl_xor(v, off);
        v = v > o ? v : o;
      }
      if (tid == 0) far_sh = 8191 - (int)(v & 0x1FFFu);
    }
    __syncthreads();
    far = far_sh;
    if (blk == 0 && tid == 0) out[b * NPT + s] = far;
  }
}

// ======================= host =======================

extern "C" void kernel_launch(void* const* d_in, const int* in_sizes, int n_in,
                              void* d_out, int out_size, void* d_ws, size_t ws_size,
                              hipStream_t stream) {
  const float* pts  = (const float*)d_in[0];
  const float* feat = (const float*)d_in[1];
  int* out = (int*)d_out;

  const size_t oneD = (size_t)NN * NN * sizeof(float);   // 256 MiB
  if (ws_size >= 2 * oneD) {
    float* D = (float*)d_ws;
    for (int b = 0; b < BB; ++b)
      dist_kernel<<<NT * NT, 256, 0, stream>>>(
          pts + (size_t)b * NN * 3, feat + (size_t)b * CC * NN, D + (size_t)b * NN * NN);
    scan_kernel<<<BB, 512, 0, stream>>>(D, (unsigned long long)NN * NN, out, NPT);
  } else if (ws_size >= oneD) {
    float* D = (float*)d_ws;
    for (int b = 0; b < BB; ++b) {
      dist_kernel<<<NT * NT, 256, 0, stream>>>(
          pts + (size_t)b * NN * 3, feat + (size_t)b * CC * NN, D);
      scan_kernel<<<1, 512, 0, stream>>>(D, 0, out + (size_t)b * NPT, 0);
    }
  } else {
    unsigned long long* slots = (unsigned long long*)d_ws; // [2][BB][NBLK] = 512 B
    hipMemsetAsync(d_ws, 0, 2 * BB * NBLK * sizeof(unsigned long long), stream);
    void* args[] = {(void*)&pts, (void*)&feat, (void*)&out, (void*)&slots};
    dim3 grid(BB * NBLK), block(TPB);
    hipLaunchCooperativeKernel((void*)fps_fallback, grid, block, args, 0, stream);
  }
}